// Round 4
// baseline (158.255 us; speedup 1.0000x reference)
//
#include <hip/hip_runtime.h>

#define B_SZ 16
#define N_BOX 96
#define EPSF 1e-7f

// ---- geometry ---------------------------------------------------------------
// level l: wl = hl = 1024 >> l, plane_px = wl*wl (16 planes each)
// streaming blocks: 8192 px/block (l0..l3), 4096 px at l4
//   l0: 0..2047 (128/plane), l1: 2048..2559 (32/plane), l2: 2560..2687 (8/plane),
//   l3: 2688..2719 (2/plane), l4: 2720..2735 (1/plane)
// correction blocks: 2736..2815, one per (b,l)
#define N_STREAM 2736
#define N_CORR   (B_SZ * 5)
#define N_BLOCKS (N_STREAM + N_CORR)

__device__ __forceinline__ const float* pick_att(
    int l, const float* a0, const float* a1, const float* a2,
    const float* a3, const float* a4)
{
    switch (l) { case 0: return a0; case 1: return a1; case 2: return a2;
                 case 3: return a3; default: return a4; }
}

// ---- kernel 1: streaming -log(1-p) + per-(b,l) rect correction --------------
__global__ __launch_bounds__(256)
void bce_all_kernel(const float* __restrict__ a0, const float* __restrict__ a1,
                    const float* __restrict__ a2, const float* __restrict__ a3,
                    const float* __restrict__ a4,
                    const float* __restrict__ bboxs,
                    const int* __restrict__ hp, const int* __restrict__ wp,
                    float* __restrict__ partial,   // [N_STREAM]
                    float* __restrict__ corr)      // [N_CORR]
{
    __shared__ float wsum[4];
    __shared__ int rx1[N_BOX], ry1[N_BOX], rx2[N_BOX], ry2[N_BOX];
    __shared__ int Rcnt;

    int bid = blockIdx.x;
    float s = 0.0f;

    if (bid < N_STREAM) {
        // ---------------- streaming pass: sum -log(1-p) ----------------------
        int l, start, bppShift;
        const float* att;
        if (bid < 2048)      { l = 0; start = 0;    bppShift = 7; att = a0; }
        else if (bid < 2560) { l = 1; start = 2048; bppShift = 5; att = a1; }
        else if (bid < 2688) { l = 2; start = 2560; bppShift = 3; att = a2; }
        else if (bid < 2720) { l = 3; start = 2688; bppShift = 1; att = a3; }
        else                 { l = 4; start = 2720; bppShift = 0; att = a4; }

        int planeF4 = 1 << (18 - 2 * l);
        int bil = bid - start;
        int chunk = bil & ((1 << bppShift) - 1);
        int nf4 = planeF4 >> bppShift;            // 2048, or 1024 at l4
        unsigned gf4base = (unsigned)(bil >> bppShift) * (unsigned)planeF4
                         + (unsigned)chunk * (unsigned)nf4 + threadIdx.x;

        if (nf4 == 2048) {
            float4 av[8];
            #pragma unroll
            for (int u = 0; u < 8; ++u)
                av[u] = reinterpret_cast<const float4*>(att)[gf4base + u * 256u];
            #pragma unroll
            for (int u = 0; u < 8; ++u) {
                float pv[4] = {av[u].x, av[u].y, av[u].z, av[u].w};
                #pragma unroll
                for (int j = 0; j < 4; ++j) {
                    float p = fminf(fmaxf(pv[j], EPSF), 1.0f - EPSF);
                    s -= __logf(1.0f - p);
                }
            }
        } else {
            float4 av[4];
            #pragma unroll
            for (int u = 0; u < 4; ++u)
                av[u] = reinterpret_cast<const float4*>(att)[gf4base + u * 256u];
            #pragma unroll
            for (int u = 0; u < 4; ++u) {
                float pv[4] = {av[u].x, av[u].y, av[u].z, av[u].w};
                #pragma unroll
                for (int j = 0; j < 4; ++j) {
                    float p = fminf(fmaxf(pv[j], EPSF), 1.0f - EPSF);
                    s -= __logf(1.0f - p);
                }
            }
        }
    } else {
        // ---------------- correction pass: masked px add log((1-p)/p) --------
        int idx = bid - N_STREAM;
        int b = idx / 5, l = idx % 5;
        const float* att = pick_att(l, a0, a1, a2, a3, a4);
        int wl = 1024 >> l;
        float Wf = (float)(*wp), Hf = (float)(*hp);

        if (threadIdx.x == 0) {
            int R = 0;
            double based = (double)(32 << l);
            float mn  = (float)(based * based * 0.5);
            float mxv = (float)((based * 1.58) * (based * 1.58) * 2.0);
            float sx = (float)wl / Wf, sy = (float)wl / Hf;
            for (int n = 0; n < N_BOX; ++n) {
                const float* bx = bboxs + (b * N_BOX + n) * 5;
                float x1 = bx[0], y1 = bx[1], x2 = bx[2], y2 = bx[3], lb = bx[4];
                if (!(lb != -1.0f && x1 <= Wf && y1 <= Hf && x2 <= Wf && y2 <= Hf))
                    continue;
                float area = (x2 - x1) * (y2 - y1);
                if (!(area >= mn && area <= mxv)) continue;
                int ix1 = (int)fmaxf(floorf(x1 * sx), 0.0f);
                int iy1 = (int)fmaxf(floorf(y1 * sy), 0.0f);
                int ix2 = (int)fminf(ceilf(x2 * sx) + 1.0f, (float)wl);
                int iy2 = (int)fminf(ceilf(y2 * sy) + 1.0f, (float)wl);
                if (ix2 <= ix1 || iy2 <= iy1) continue;
                rx1[R] = ix1; ry1[R] = iy1; rx2[R] = ix2; ry2[R] = iy2; ++R;
            }
            Rcnt = R;
        }
        __syncthreads();

        unsigned pbase = (unsigned)b << (20 - 2 * l);
        for (int r = 0; r < Rcnt; ++r) {          // Rcnt uniform (LDS)
            int w = rx2[r] - rx1[r];
            int npx = w * (ry2[r] - ry1[r]);
            for (int i = (int)threadIdx.x; i < npx; i += 256) {
                int y = ry1[r] + i / w;
                int x = rx1[r] + i % w;
                bool dup = false;
                for (int q = 0; q < r; ++q)       // first-hit dedup (union)
                    dup |= (x >= rx1[q] && x < rx2[q] && y >= ry1[q] && y < ry2[q]);
                if (dup) continue;
                float p = att[pbase + (unsigned)y * (unsigned)wl + (unsigned)x];
                p = fminf(fmaxf(p, EPSF), 1.0f - EPSF);
                s += __logf(1.0f - p) - __logf(p);   // -log(p) - (-log(1-p))
            }
        }
    }

    // ---- block reduce (wave shuffle + LDS across 4 waves) -------------------
    #pragma unroll
    for (int off = 32; off > 0; off >>= 1)
        s += __shfl_down(s, off, 64);
    int lane = threadIdx.x & 63, wv = threadIdx.x >> 6;
    if (lane == 0) wsum[wv] = s;
    __syncthreads();
    if (threadIdx.x == 0) {
        float t = wsum[0] + wsum[1] + wsum[2] + wsum[3];
        if (bid < N_STREAM) partial[bid] = t;
        else                corr[bid - N_STREAM] = t;
    }
}

// ---- kernel 2: finalize ------------------------------------------------------
__global__ __launch_bounds__(256)
void finalize_kernel(const float* __restrict__ bboxs,
                     const int* __restrict__ hp, const int* __restrict__ wp,
                     const float* __restrict__ partial,
                     const float* __restrict__ corr,
                     float* __restrict__ out)
{
    __shared__ int hasbox[B_SZ];
    __shared__ double red[256];
    if (threadIdx.x < B_SZ) hasbox[threadIdx.x] = 0;
    __syncthreads();
    float Wf = (float)(*wp), Hf = (float)(*hp);
    for (int i = (int)threadIdx.x; i < B_SZ * N_BOX; i += 256) {
        const float* bx = bboxs + i * 5;
        if (bx[4] != -1.0f && bx[0] <= Wf && bx[1] <= Hf && bx[2] <= Wf && bx[3] <= Hf)
            hasbox[i / N_BOX] = 1;        // benign race, same value
    }
    __syncthreads();

    double t = 0.0;
    for (int i = (int)threadIdx.x; i < N_STREAM; i += 256) {
        int l, start, bppShift;
        if (i < 2048)      { l = 0; start = 0;    bppShift = 7; }
        else if (i < 2560) { l = 1; start = 2048; bppShift = 5; }
        else if (i < 2688) { l = 2; start = 2560; bppShift = 3; }
        else if (i < 2720) { l = 3; start = 2688; bppShift = 1; }
        else               { l = 4; start = 2720; bppShift = 0; }
        int b = (i - start) >> bppShift;
        if (hasbox[b]) {
            int wl = 1024 >> l;
            t += (double)partial[i] / (double)(wl * wl);
        }
    }
    for (int i = (int)threadIdx.x; i < N_CORR; i += 256) {
        int b = i / 5, l = i % 5;
        if (hasbox[b]) {
            int wl = 1024 >> l;
            t += (double)corr[i] / (double)(wl * wl);
        }
    }
    red[threadIdx.x] = t;
    __syncthreads();
    for (int off = 128; off > 0; off >>= 1) {
        if ((int)threadIdx.x < off) red[threadIdx.x] += red[threadIdx.x + off];
        __syncthreads();
    }
    if (threadIdx.x == 0)
        out[0] = (float)(red[0] / (5.0 * (double)B_SZ));
}

// ---- launch ------------------------------------------------------------------
extern "C" void kernel_launch(void* const* d_in, const int* in_sizes, int n_in,
                              void* d_out, int out_size, void* d_ws, size_t ws_size,
                              hipStream_t stream)
{
    const float* a0 = (const float*)d_in[0];
    const float* a1 = (const float*)d_in[1];
    const float* a2 = (const float*)d_in[2];
    const float* a3 = (const float*)d_in[3];
    const float* a4 = (const float*)d_in[4];
    const float* bboxs = (const float*)d_in[5];
    const int* hp = (const int*)d_in[6];
    const int* wp = (const int*)d_in[7];

    float* partial = (float*)d_ws;            // N_STREAM floats, all written
    float* corr    = partial + N_STREAM;      // N_CORR floats, all written

    bce_all_kernel<<<N_BLOCKS, 256, 0, stream>>>(a0, a1, a2, a3, a4,
                                                 bboxs, hp, wp, partial, corr);
    finalize_kernel<<<1, 256, 0, stream>>>(bboxs, hp, wp, partial, corr,
                                           (float*)d_out);
}

// Round 5
// 104.474 us; speedup vs baseline: 1.5148x; 1.5148x over previous
//
#include <hip/hip_runtime.h>

#define B_SZ 16
#define N_BOX 96
#define EPSF 1e-7f

// ---- geometry ---------------------------------------------------------------
// level l: wl = hl = 1024 >> l, plane_px = wl*wl (16 planes each)
// grid: blocks 0..79 = correction (one per (b,l));
//       blocks 80..2815 = streaming, sbid = bid-80:
//   l0: 0..2047 (128/plane), l1: 2048..2559 (32/plane), l2: 2560..2687 (8/plane),
//   l3: 2688..2719 (2/plane), l4: 2720..2735 (1/plane)
#define N_CORR   (B_SZ * 5)
#define N_STREAM 2736
#define N_BLOCKS (N_CORR + N_STREAM)

__device__ __forceinline__ const float* pick_att(
    int l, const float* a0, const float* a1, const float* a2,
    const float* a3, const float* a4)
{
    switch (l) { case 0: return a0; case 1: return a1; case 2: return a2;
                 case 3: return a3; default: return a4; }
}

// ---- kernel 1: streaming -log(1-p) + per-(b,l) rect correction --------------
__global__ __launch_bounds__(256)
void bce_all_kernel(const float* __restrict__ a0, const float* __restrict__ a1,
                    const float* __restrict__ a2, const float* __restrict__ a3,
                    const float* __restrict__ a4,
                    const float* __restrict__ bboxs,
                    const int* __restrict__ hp, const int* __restrict__ wp,
                    float* __restrict__ partial,   // [N_STREAM]
                    float* __restrict__ corr)      // [N_CORR]
{
    __shared__ float wsum[4];

    int bid = blockIdx.x;
    float s = 0.0f;

    if (bid >= N_CORR) {
        // ---------------- streaming pass: sum -log(1-p) ----------------------
        int sbid = bid - N_CORR;
        int l, start, bppShift;
        const float* att;
        if (sbid < 2048)      { l = 0; start = 0;    bppShift = 7; att = a0; }
        else if (sbid < 2560) { l = 1; start = 2048; bppShift = 5; att = a1; }
        else if (sbid < 2688) { l = 2; start = 2560; bppShift = 3; att = a2; }
        else if (sbid < 2720) { l = 3; start = 2688; bppShift = 1; att = a3; }
        else                  { l = 4; start = 2720; bppShift = 0; att = a4; }

        int planeF4 = 1 << (18 - 2 * l);
        int bil = sbid - start;
        int chunk = bil & ((1 << bppShift) - 1);
        int nf4 = planeF4 >> bppShift;            // 2048, or 1024 at l4
        unsigned gf4base = (unsigned)(bil >> bppShift) * (unsigned)planeF4
                         + (unsigned)chunk * (unsigned)nf4 + threadIdx.x;

        if (nf4 == 2048) {
            float4 av[8];
            #pragma unroll
            for (int u = 0; u < 8; ++u)
                av[u] = reinterpret_cast<const float4*>(att)[gf4base + u * 256u];
            #pragma unroll
            for (int u = 0; u < 8; ++u) {
                float q0 = 1.0f - fminf(fmaxf(av[u].x, EPSF), 1.0f - EPSF);
                float q1 = 1.0f - fminf(fmaxf(av[u].y, EPSF), 1.0f - EPSF);
                float q2 = 1.0f - fminf(fmaxf(av[u].z, EPSF), 1.0f - EPSF);
                float q3 = 1.0f - fminf(fmaxf(av[u].w, EPSF), 1.0f - EPSF);
                s -= __logf((q0 * q1) * (q2 * q3));   // >= 1e-28, no underflow
            }
        } else {
            float4 av[4];
            #pragma unroll
            for (int u = 0; u < 4; ++u)
                av[u] = reinterpret_cast<const float4*>(att)[gf4base + u * 256u];
            #pragma unroll
            for (int u = 0; u < 4; ++u) {
                float q0 = 1.0f - fminf(fmaxf(av[u].x, EPSF), 1.0f - EPSF);
                float q1 = 1.0f - fminf(fmaxf(av[u].y, EPSF), 1.0f - EPSF);
                float q2 = 1.0f - fminf(fmaxf(av[u].z, EPSF), 1.0f - EPSF);
                float q3 = 1.0f - fminf(fmaxf(av[u].w, EPSF), 1.0f - EPSF);
                s -= __logf((q0 * q1) * (q2 * q3));
            }
        }
    } else {
        // ---------------- correction pass: masked px add log((1-p)/p) --------
        __shared__ int brx1[N_BOX], bry1[N_BOX], brx2[N_BOX], bry2[N_BOX];
        __shared__ int bok[N_BOX];
        __shared__ int rx1[N_BOX], ry1[N_BOX], rx2[N_BOX], ry2[N_BOX];
        __shared__ int pfx[N_BOX + 1];
        __shared__ int Rcnt, Tpx;

        int b = bid / 5, l = bid % 5;
        const float* att = pick_att(l, a0, a1, a2, a3, a4);
        int wl = 1024 >> l;
        float Wf = (float)(*wp), Hf = (float)(*hp);

        // parallel gate+raster: one lane per box
        if (threadIdx.x < N_BOX) {
            int n = threadIdx.x;
            const float* bx = bboxs + (b * N_BOX + n) * 5;
            float x1 = bx[0], y1 = bx[1], x2 = bx[2], y2 = bx[3], lb = bx[4];
            double based = (double)(32 << l);
            float mn  = (float)(based * based * 0.5);
            float mxv = (float)((based * 1.58) * (based * 1.58) * 2.0);
            float area = (x2 - x1) * (y2 - y1);
            bool ok = (lb != -1.0f) && (x1 <= Wf) && (y1 <= Hf) &&
                      (x2 <= Wf) && (y2 <= Hf) && (area >= mn) && (area <= mxv);
            float sx = (float)wl / Wf, sy = (float)wl / Hf;
            int ix1 = (int)fmaxf(floorf(x1 * sx), 0.0f);
            int iy1 = (int)fmaxf(floorf(y1 * sy), 0.0f);
            int ix2 = (int)fminf(ceilf(x2 * sx) + 1.0f, (float)wl);
            int iy2 = (int)fminf(ceilf(y2 * sy) + 1.0f, (float)wl);
            ok = ok && (ix2 > ix1) && (iy2 > iy1);
            bok[n] = ok ? 1 : 0;
            brx1[n] = ix1; bry1[n] = iy1; brx2[n] = ix2; bry2[n] = iy2;
        }
        __syncthreads();

        // compact + prefix (LDS-only, one thread, ~R*const cycles)
        if (threadIdx.x == 0) {
            int R = 0, T = 0;
            for (int n = 0; n < N_BOX; ++n) {
                if (!bok[n]) continue;
                rx1[R] = brx1[n]; ry1[R] = bry1[n];
                rx2[R] = brx2[n]; ry2[R] = bry2[n];
                pfx[R] = T;
                T += (brx2[n] - brx1[n]) * (bry2[n] - bry1[n]);
                ++R;
            }
            pfx[R] = T; Rcnt = R; Tpx = T;
        }
        __syncthreads();

        // flattened masked-pixel loop: independent iterations, pipelined loads
        unsigned pbase = (unsigned)b << (20 - 2 * l);
        int T = Tpx, R = Rcnt;
        for (int i = (int)threadIdx.x; i < T; i += 256) {
            int lo = 0, hi = R - 1;
            while (lo < hi) {                      // find r: pfx[r] <= i < pfx[r+1]
                int mid = (lo + hi + 1) >> 1;
                if (pfx[mid] <= i) lo = mid; else hi = mid - 1;
            }
            int r = lo;
            int rem = i - pfx[r];
            int w = rx2[r] - rx1[r];
            int y = ry1[r] + rem / w;
            int x = rx1[r] + rem % w;
            bool dup = false;
            for (int q = 0; q < r; ++q)            // first-hit dedup (union)
                dup |= (x >= rx1[q] && x < rx2[q] && y >= ry1[q] && y < ry2[q]);
            if (!dup) {
                float p = att[pbase + (unsigned)y * (unsigned)wl + (unsigned)x];
                p = fminf(fmaxf(p, EPSF), 1.0f - EPSF);
                s += __logf((1.0f - p) / p);       // -log(p) - (-log(1-p))
            }
        }
    }

    // ---- block reduce (wave shuffle + LDS across 4 waves) -------------------
    #pragma unroll
    for (int off = 32; off > 0; off >>= 1)
        s += __shfl_down(s, off, 64);
    int lane = threadIdx.x & 63, wv = threadIdx.x >> 6;
    if (lane == 0) wsum[wv] = s;
    __syncthreads();
    if (threadIdx.x == 0) {
        float t = wsum[0] + wsum[1] + wsum[2] + wsum[3];
        if (bid < N_CORR) corr[bid] = t;
        else              partial[bid - N_CORR] = t;
    }
}

// ---- kernel 2: finalize ------------------------------------------------------
__global__ __launch_bounds__(256)
void finalize_kernel(const float* __restrict__ bboxs,
                     const int* __restrict__ hp, const int* __restrict__ wp,
                     const float* __restrict__ partial,
                     const float* __restrict__ corr,
                     float* __restrict__ out)
{
    __shared__ int hasbox[B_SZ];
    __shared__ double red[256];
    if (threadIdx.x < B_SZ) hasbox[threadIdx.x] = 0;
    __syncthreads();
    float Wf = (float)(*wp), Hf = (float)(*hp);
    for (int i = (int)threadIdx.x; i < B_SZ * N_BOX; i += 256) {
        const float* bx = bboxs + i * 5;
        if (bx[4] != -1.0f && bx[0] <= Wf && bx[1] <= Hf && bx[2] <= Wf && bx[3] <= Hf)
            hasbox[i / N_BOX] = 1;        // benign race, same value
    }
    __syncthreads();

    double t = 0.0;
    for (int i = (int)threadIdx.x; i < N_STREAM; i += 256) {
        int l, start, bppShift;
        if (i < 2048)      { l = 0; start = 0;    bppShift = 7; }
        else if (i < 2560) { l = 1; start = 2048; bppShift = 5; }
        else if (i < 2688) { l = 2; start = 2560; bppShift = 3; }
        else if (i < 2720) { l = 3; start = 2688; bppShift = 1; }
        else               { l = 4; start = 2720; bppShift = 0; }
        int b = (i - start) >> bppShift;
        if (hasbox[b]) {
            int wl = 1024 >> l;
            t += (double)partial[i] / (double)(wl * wl);
        }
    }
    for (int i = (int)threadIdx.x; i < N_CORR; i += 256) {
        int b = i / 5, l = i % 5;
        if (hasbox[b]) {
            int wl = 1024 >> l;
            t += (double)corr[i] / (double)(wl * wl);
        }
    }
    red[threadIdx.x] = t;
    __syncthreads();
    for (int off = 128; off > 0; off >>= 1) {
        if ((int)threadIdx.x < off) red[threadIdx.x] += red[threadIdx.x + off];
        __syncthreads();
    }
    if (threadIdx.x == 0)
        out[0] = (float)(red[0] / (5.0 * (double)B_SZ));
}

// ---- launch ------------------------------------------------------------------
extern "C" void kernel_launch(void* const* d_in, const int* in_sizes, int n_in,
                              void* d_out, int out_size, void* d_ws, size_t ws_size,
                              hipStream_t stream)
{
    const float* a0 = (const float*)d_in[0];
    const float* a1 = (const float*)d_in[1];
    const float* a2 = (const float*)d_in[2];
    const float* a3 = (const float*)d_in[3];
    const float* a4 = (const float*)d_in[4];
    const float* bboxs = (const float*)d_in[5];
    const int* hp = (const int*)d_in[6];
    const int* wp = (const int*)d_in[7];

    float* partial = (float*)d_ws;            // N_STREAM floats, all written
    float* corr    = partial + N_STREAM;      // N_CORR floats, all written

    bce_all_kernel<<<N_BLOCKS, 256, 0, stream>>>(a0, a1, a2, a3, a4,
                                                 bboxs, hp, wp, partial, corr);
    finalize_kernel<<<1, 256, 0, stream>>>(bboxs, hp, wp, partial, corr,
                                           (float*)d_out);
}

// Round 6
// 69.273 us; speedup vs baseline: 2.2845x; 1.5082x over previous
//
#include <hip/hip_runtime.h>

#define B_SZ 16
#define N_BOX 96
#define EPSF 1e-7f

// ---- geometry ---------------------------------------------------------------
// level l: wl = hl = 1024 >> l, plane_px = wl*wl (16 planes each)
// Correction blocks (bids 0..207), LDS row-slice bitmask per block:
//   l0: 8 slices x 16 b = 128 (SROWS=128), l1: 2 x 16 = 32 (SROWS=256),
//   l2: 16 (SROWS=256), l3: 16 (SROWS=128), l4: 16 (SROWS=64)
// Streaming blocks (bids 208..2943), sbid = bid-208:
//   l0: 0..2047 (128/plane), l1: 2048..2559, l2: 2560..2687,
//   l3: 2688..2719, l4: 2720..2735
#define N_CORR2  208
#define N_STREAM 2736
#define N_BLOCKS (N_CORR2 + N_STREAM)

__device__ __forceinline__ const float* pick_att(
    int l, const float* a0, const float* a1, const float* a2,
    const float* a3, const float* a4)
{
    switch (l) { case 0: return a0; case 1: return a1; case 2: return a2;
                 case 3: return a3; default: return a4; }
}

// ---- kernel 1: streaming -log(1-p)  +  slice-bitmask correction -------------
__global__ __launch_bounds__(256)
void bce_all_kernel(const float* __restrict__ a0, const float* __restrict__ a1,
                    const float* __restrict__ a2, const float* __restrict__ a3,
                    const float* __restrict__ a4,
                    const float* __restrict__ bboxs,
                    const int* __restrict__ hp, const int* __restrict__ wp,
                    float* __restrict__ partial,   // [N_STREAM]
                    float* __restrict__ corr)      // [N_CORR2]
{
    __shared__ unsigned mask[4096];                // 16 KB slice bitmask
    __shared__ int brx1[N_BOX], bry1[N_BOX], brx2[N_BOX], bry2[N_BOX];
    __shared__ int bok[N_BOX];
    __shared__ float wsum[4];

    int bid = blockIdx.x;
    float s = 0.0f;

    if (bid >= N_CORR2) {
        // ---------------- streaming: sum -log(1-p) over all pixels -----------
        int sbid = bid - N_CORR2;
        int l, start, bppShift;
        const float* att;
        if (sbid < 2048)      { l = 0; start = 0;    bppShift = 7; att = a0; }
        else if (sbid < 2560) { l = 1; start = 2048; bppShift = 5; att = a1; }
        else if (sbid < 2688) { l = 2; start = 2560; bppShift = 3; att = a2; }
        else if (sbid < 2720) { l = 3; start = 2688; bppShift = 1; att = a3; }
        else                  { l = 4; start = 2720; bppShift = 0; att = a4; }

        int planeF4 = 1 << (18 - 2 * l);
        int bil = sbid - start;
        int chunk = bil & ((1 << bppShift) - 1);
        int nf4 = planeF4 >> bppShift;            // 2048, or 1024 at l4
        unsigned gf4base = (unsigned)(bil >> bppShift) * (unsigned)planeF4
                         + (unsigned)chunk * (unsigned)nf4 + threadIdx.x;

        if (nf4 == 2048) {
            float4 av[8];
            #pragma unroll
            for (int u = 0; u < 8; ++u)
                av[u] = reinterpret_cast<const float4*>(att)[gf4base + u * 256u];
            #pragma unroll
            for (int u = 0; u < 8; ++u) {
                float q0 = 1.0f - fminf(fmaxf(av[u].x, EPSF), 1.0f - EPSF);
                float q1 = 1.0f - fminf(fmaxf(av[u].y, EPSF), 1.0f - EPSF);
                float q2 = 1.0f - fminf(fmaxf(av[u].z, EPSF), 1.0f - EPSF);
                float q3 = 1.0f - fminf(fmaxf(av[u].w, EPSF), 1.0f - EPSF);
                s -= __logf((q0 * q1) * (q2 * q3));   // >= 1e-28, no underflow
            }
        } else {
            float4 av[4];
            #pragma unroll
            for (int u = 0; u < 4; ++u)
                av[u] = reinterpret_cast<const float4*>(att)[gf4base + u * 256u];
            #pragma unroll
            for (int u = 0; u < 4; ++u) {
                float q0 = 1.0f - fminf(fmaxf(av[u].x, EPSF), 1.0f - EPSF);
                float q1 = 1.0f - fminf(fmaxf(av[u].y, EPSF), 1.0f - EPSF);
                float q2 = 1.0f - fminf(fmaxf(av[u].z, EPSF), 1.0f - EPSF);
                float q3 = 1.0f - fminf(fmaxf(av[u].w, EPSF), 1.0f - EPSF);
                s -= __logf((q0 * q1) * (q2 * q3));
            }
        }
    } else {
        // ---------------- correction: masked px add log((1-p)/p) -------------
        int c = bid, l, b, srows, y0;
        if (c < 128)      { l = 0; b = c >> 3;         srows = 128; y0 = (c & 7) * 128; }
        else if (c < 160) { l = 1; b = (c - 128) >> 1; srows = 256; y0 = ((c - 128) & 1) * 256; }
        else if (c < 176) { l = 2; b = c - 160;        srows = 256; y0 = 0; }
        else if (c < 192) { l = 3; b = c - 176;        srows = 128; y0 = 0; }
        else              { l = 4; b = c - 192;        srows = 64;  y0 = 0; }

        const float* att = pick_att(l, a0, a1, a2, a3, a4);
        int wl = 1024 >> l;
        int wpr = wl >> 5;                        // words per row
        int sliceWords = srows * wpr;             // <= 4096
        float Wf = (float)(*wp), Hf = (float)(*hp);

        // gate + raster boxes to integer rects (one lane per box)
        if (threadIdx.x < N_BOX) {
            int n = threadIdx.x;
            const float* bx = bboxs + (b * N_BOX + n) * 5;
            float x1 = bx[0], y1 = bx[1], x2 = bx[2], y2 = bx[3], lb = bx[4];
            double based = (double)(32 << l);
            float mn  = (float)(based * based * 0.5);
            float mxv = (float)((based * 1.58) * (based * 1.58) * 2.0);
            float area = (x2 - x1) * (y2 - y1);
            bool ok = (lb != -1.0f) && (x1 <= Wf) && (y1 <= Hf) &&
                      (x2 <= Wf) && (y2 <= Hf) && (area >= mn) && (area <= mxv);
            float sx = (float)wl / Wf, sy = (float)wl / Hf;
            int ix1 = (int)fmaxf(floorf(x1 * sx), 0.0f);
            int iy1 = (int)fmaxf(floorf(y1 * sy), 0.0f);
            int ix2 = (int)fminf(ceilf(x2 * sx) + 1.0f, (float)wl);
            int iy2 = (int)fminf(ceilf(y2 * sy) + 1.0f, (float)wl);
            ok = ok && (ix2 > ix1) && (iy2 > iy1);
            bok[n] = ok ? 1 : 0;
            brx1[n] = ix1; bry1[n] = iy1; brx2[n] = ix2; bry2[n] = iy2;
        }
        // clear slice bitmask (all threads)
        for (int j = (int)threadIdx.x; j < sliceWords; j += 256) mask[j] = 0u;
        __syncthreads();

        // rasterize: thread t owns row y0+t; rect coords uniform per iteration
        int t = (int)threadIdx.x;
        int y = y0 + t;
        for (int r = 0; r < N_BOX; ++r) {
            if (!bok[r]) continue;                         // uniform
            bool inRow = (t < srows) && (y >= bry1[r]) && (y < bry2[r]);
            int x1i = brx1[r], x2i = brx2[r];              // uniform
            int w0 = x1i >> 5, w1 = (x2i - 1) >> 5;        // uniform
            for (int w = w0; w <= w1; ++w) {               // uniform bounds
                unsigned lo = (w == w0) ? (unsigned)(x1i & 31) : 0u;
                unsigned hi = (w == w1) ? (unsigned)(((x2i - 1) & 31) + 1) : 32u;
                unsigned m = (hi == 32u ? 0xffffffffu : ((1u << hi) - 1u))
                           & ~((1u << lo) - 1u);
                if (inRow) mask[t * wpr + w] |= m;         // row-owned, no atomic
            }
        }
        __syncthreads();

        // scan set bits -> independent global loads
        unsigned pbase = (unsigned)b << (20 - 2 * l);
        int wprShift = 5 - l;                     // log2(wpr): 5,4,3,2,1
        for (int j = (int)threadIdx.x; j < sliceWords; j += 256) {
            unsigned wv = mask[j];
            if (!wv) continue;
            int yy = y0 + (j >> wprShift);
            int xb = (j & (wpr - 1)) << 5;
            unsigned base = pbase + (unsigned)yy * (unsigned)wl + (unsigned)xb;
            while (wv) {
                int bit = __ffs(wv) - 1;
                wv &= wv - 1u;
                float p = att[base + (unsigned)bit];
                p = fminf(fmaxf(p, EPSF), 1.0f - EPSF);
                s += __logf(1.0f - p) - __logf(p);
            }
        }
    }

    // ---- block reduce (wave shuffle + LDS across 4 waves) -------------------
    #pragma unroll
    for (int off = 32; off > 0; off >>= 1)
        s += __shfl_down(s, off, 64);
    int lane = threadIdx.x & 63, wv2 = threadIdx.x >> 6;
    if (lane == 0) wsum[wv2] = s;
    __syncthreads();
    if (threadIdx.x == 0) {
        float tt = wsum[0] + wsum[1] + wsum[2] + wsum[3];
        if (bid < N_CORR2) corr[bid] = tt;
        else               partial[bid - N_CORR2] = tt;
    }
}

// ---- kernel 2: finalize ------------------------------------------------------
__global__ __launch_bounds__(256)
void finalize_kernel(const float* __restrict__ bboxs,
                     const int* __restrict__ hp, const int* __restrict__ wp,
                     const float* __restrict__ partial,
                     const float* __restrict__ corr,
                     float* __restrict__ out)
{
    __shared__ int hasbox[B_SZ];
    __shared__ double red[256];
    if (threadIdx.x < B_SZ) hasbox[threadIdx.x] = 0;
    __syncthreads();
    float Wf = (float)(*wp), Hf = (float)(*hp);
    for (int i = (int)threadIdx.x; i < B_SZ * N_BOX; i += 256) {
        const float* bx = bboxs + i * 5;
        if (bx[4] != -1.0f && bx[0] <= Wf && bx[1] <= Hf && bx[2] <= Wf && bx[3] <= Hf)
            hasbox[i / N_BOX] = 1;        // benign race, same value
    }
    __syncthreads();

    double t = 0.0;
    for (int i = (int)threadIdx.x; i < N_STREAM; i += 256) {
        int l, start, bppShift;
        if (i < 2048)      { l = 0; start = 0;    bppShift = 7; }
        else if (i < 2560) { l = 1; start = 2048; bppShift = 5; }
        else if (i < 2688) { l = 2; start = 2560; bppShift = 3; }
        else if (i < 2720) { l = 3; start = 2688; bppShift = 1; }
        else               { l = 4; start = 2720; bppShift = 0; }
        int b = (i - start) >> bppShift;
        if (hasbox[b]) {
            int wl = 1024 >> l;
            t += (double)partial[i] / (double)(wl * wl);
        }
    }
    for (int i = (int)threadIdx.x; i < N_CORR2; i += 256) {
        int l, b;
        if (i < 128)      { l = 0; b = i >> 3; }
        else if (i < 160) { l = 1; b = (i - 128) >> 1; }
        else if (i < 176) { l = 2; b = i - 160; }
        else if (i < 192) { l = 3; b = i - 176; }
        else              { l = 4; b = i - 192; }
        if (hasbox[b]) {
            int wl = 1024 >> l;
            t += (double)corr[i] / (double)(wl * wl);
        }
    }
    red[threadIdx.x] = t;
    __syncthreads();
    for (int off = 128; off > 0; off >>= 1) {
        if ((int)threadIdx.x < off) red[threadIdx.x] += red[threadIdx.x + off];
        __syncthreads();
    }
    if (threadIdx.x == 0)
        out[0] = (float)(red[0] / (5.0 * (double)B_SZ));
}

// ---- launch ------------------------------------------------------------------
extern "C" void kernel_launch(void* const* d_in, const int* in_sizes, int n_in,
                              void* d_out, int out_size, void* d_ws, size_t ws_size,
                              hipStream_t stream)
{
    const float* a0 = (const float*)d_in[0];
    const float* a1 = (const float*)d_in[1];
    const float* a2 = (const float*)d_in[2];
    const float* a3 = (const float*)d_in[3];
    const float* a4 = (const float*)d_in[4];
    const float* bboxs = (const float*)d_in[5];
    const int* hp = (const int*)d_in[6];
    const int* wp = (const int*)d_in[7];

    float* partial = (float*)d_ws;            // N_STREAM floats, all written
    float* corr    = partial + N_STREAM;      // N_CORR2 floats, all written

    bce_all_kernel<<<N_BLOCKS, 256, 0, stream>>>(a0, a1, a2, a3, a4,
                                                 bboxs, hp, wp, partial, corr);
    finalize_kernel<<<1, 256, 0, stream>>>(bboxs, hp, wp, partial, corr,
                                           (float*)d_out);
}

// Round 7
// 55.871 us; speedup vs baseline: 2.8325x; 1.2399x over previous
//
#include <hip/hip_runtime.h>

#define B_SZ 16
#define N_BOX 96
#define EPSF 1e-7f

// ---- geometry ---------------------------------------------------------------
// level l: wl = hl = 1024 >> l, plane_px = wl*wl (16 planes each)
// corr blocks (208), LDS row-slice visited-bitmask per block:
//   l0: 8 slices x 16 b (srows=128), l1: 2 x 16 (srows=256),
//   l2: 16 (srows=256), l3: 16 (srows=128), l4: 16 (srows=64)
// stream blocks (2736):
//   l0: 0..2047 (128/plane), l1: 2048..2559 (32/plane), l2: 2560..2687 (8/plane),
//   l3: 2688..2719 (2/plane), l4: 2720..2735 (1/plane)
#define N_CORR2  208
#define N_STREAM 2736

__device__ __forceinline__ const float* pick_att(
    int l, const float* a0, const float* a1, const float* a2,
    const float* a3, const float* a4)
{
    switch (l) { case 0: return a0; case 1: return a1; case 2: return a2;
                 case 3: return a3; default: return a4; }
}

__device__ __forceinline__ float block_reduce(float s, float* wsum) {
    #pragma unroll
    for (int off = 32; off > 0; off >>= 1)
        s += __shfl_down(s, off, 64);
    int lane = threadIdx.x & 63, wv = threadIdx.x >> 6;
    if (lane == 0) wsum[wv] = s;
    __syncthreads();
    return wsum[0] + wsum[1] + wsum[2] + wsum[3];
}

// ---- kernel A: correction — masked px add log((1-p)/p), visited-set dedup ---
__global__ __launch_bounds__(256)
void corr_kernel(const float* __restrict__ a0, const float* __restrict__ a1,
                 const float* __restrict__ a2, const float* __restrict__ a3,
                 const float* __restrict__ a4,
                 const float* __restrict__ bboxs,
                 const int* __restrict__ hp, const int* __restrict__ wp,
                 float* __restrict__ corr)      // [N_CORR2]
{
    __shared__ unsigned mask[4096];             // 16 KB visited bitmask
    __shared__ int rx1[N_BOX], ry1[N_BOX], rx2[N_BOX], ry2[N_BOX];
    __shared__ unsigned actw[3];
    __shared__ float wsum[4];

    int c = blockIdx.x, l, b, srows, y0;
    if (c < 128)      { l = 0; b = c >> 3;         srows = 128; y0 = (c & 7) * 128; }
    else if (c < 160) { l = 1; b = (c - 128) >> 1; srows = 256; y0 = ((c - 128) & 1) * 256; }
    else if (c < 176) { l = 2; b = c - 160;        srows = 256; y0 = 0; }
    else if (c < 192) { l = 3; b = c - 176;        srows = 128; y0 = 0; }
    else              { l = 4; b = c - 192;        srows = 64;  y0 = 0; }

    const float* att = pick_att(l, a0, a1, a2, a3, a4);
    int wl = 1024 >> l;
    int wpr = wl >> 5;                          // words per row
    int sliceWords = srows * wpr;               // <= 4096
    float Wf = (float)(*wp), Hf = (float)(*hp);

    if (threadIdx.x < 3) actw[threadIdx.x] = 0u;
    for (int j = (int)threadIdx.x; j < sliceWords; j += 256) mask[j] = 0u;
    __syncthreads();

    // gate + raster boxes to integer rects (one lane per box)
    if (threadIdx.x < N_BOX) {
        int n = threadIdx.x;
        const float* bx = bboxs + (b * N_BOX + n) * 5;
        float x1 = bx[0], y1 = bx[1], x2 = bx[2], y2 = bx[3], lb = bx[4];
        double based = (double)(32 << l);
        float mn  = (float)(based * based * 0.5);
        float mxv = (float)((based * 1.58) * (based * 1.58) * 2.0);
        float area = (x2 - x1) * (y2 - y1);
        bool ok = (lb != -1.0f) && (x1 <= Wf) && (y1 <= Hf) &&
                  (x2 <= Wf) && (y2 <= Hf) && (area >= mn) && (area <= mxv);
        float sx = (float)wl / Wf, sy = (float)wl / Hf;
        int ix1 = (int)fmaxf(floorf(x1 * sx), 0.0f);
        int iy1 = (int)fmaxf(floorf(y1 * sy), 0.0f);
        int ix2 = (int)fminf(ceilf(x2 * sx) + 1.0f, (float)wl);
        int iy2 = (int)fminf(ceilf(y2 * sy) + 1.0f, (float)wl);
        ok = ok && (ix2 > ix1) && (iy2 > iy1);
        rx1[n] = ix1; ry1[n] = iy1; rx2[n] = ix2; ry2[n] = iy2;
        if (ok) atomicOr(&actw[n >> 5], 1u << (n & 31));
    }
    __syncthreads();

    unsigned aw0 = actw[0], aw1 = actw[1], aw2 = actw[2];   // register skip mask
    unsigned pbase = (unsigned)b << (20 - 2 * l);
    int wvid = (int)(threadIdx.x >> 6), lane = (int)(threadIdx.x & 63);
    float s = 0.0f;

    // wave-per-rect gather with first-touch dedup (exact union, any data)
    for (int r = wvid; r < N_BOX; r += 4) {
        unsigned aw = (r < 32) ? aw0 : (r < 64) ? aw1 : aw2;
        if (!((aw >> (r & 31)) & 1u)) continue;
        int x1i = rx1[r], x2i = rx2[r];
        int ys = max(ry1[r], y0), ye = min(ry2[r], y0 + srows);
        int w = x2i - x1i, npx = w * (ye - ys);
        for (int i = lane; i < npx; i += 64) {
            int yy = ys + i / w;
            int xx = x1i + i % w;
            int widx = (yy - y0) * wpr + (xx >> 5);
            unsigned bit = 1u << (xx & 31);
            unsigned old = atomicOr(&mask[widx], bit);
            if (!(old & bit)) {
                float p = att[pbase + (unsigned)yy * (unsigned)wl + (unsigned)xx];
                p = fminf(fmaxf(p, EPSF), 1.0f - EPSF);
                s += __logf((1.0f - p) / p);
            }
        }
    }

    float t = block_reduce(s, wsum);
    if (threadIdx.x == 0) corr[c] = t;
}

// ---- kernel B: pure streaming sum of -log(1-p) ------------------------------
__global__ __launch_bounds__(256)
void stream_kernel(const float* __restrict__ a0, const float* __restrict__ a1,
                   const float* __restrict__ a2, const float* __restrict__ a3,
                   const float* __restrict__ a4,
                   float* __restrict__ partial)   // [N_STREAM]
{
    __shared__ float wsum[4];
    int sbid = blockIdx.x;
    int l, start, bppShift;
    const float* att;
    if (sbid < 2048)      { l = 0; start = 0;    bppShift = 7; att = a0; }
    else if (sbid < 2560) { l = 1; start = 2048; bppShift = 5; att = a1; }
    else if (sbid < 2688) { l = 2; start = 2560; bppShift = 3; att = a2; }
    else if (sbid < 2720) { l = 3; start = 2688; bppShift = 1; att = a3; }
    else                  { l = 4; start = 2720; bppShift = 0; att = a4; }

    int planeF4 = 1 << (18 - 2 * l);
    int bil = sbid - start;
    int chunk = bil & ((1 << bppShift) - 1);
    int nf4 = planeF4 >> bppShift;              // 2048, or 1024 at l4
    unsigned gf4base = (unsigned)(bil >> bppShift) * (unsigned)planeF4
                     + (unsigned)chunk * (unsigned)nf4 + threadIdx.x;

    float s = 0.0f;
    if (nf4 == 2048) {
        float4 av[8];
        #pragma unroll
        for (int u = 0; u < 8; ++u)
            av[u] = reinterpret_cast<const float4*>(att)[gf4base + u * 256u];
        #pragma unroll
        for (int u = 0; u < 8; ++u) {
            float q0 = 1.0f - fminf(fmaxf(av[u].x, EPSF), 1.0f - EPSF);
            float q1 = 1.0f - fminf(fmaxf(av[u].y, EPSF), 1.0f - EPSF);
            float q2 = 1.0f - fminf(fmaxf(av[u].z, EPSF), 1.0f - EPSF);
            float q3 = 1.0f - fminf(fmaxf(av[u].w, EPSF), 1.0f - EPSF);
            s -= __logf((q0 * q1) * (q2 * q3));     // >= 1e-28, no underflow
        }
    } else {
        float4 av[4];
        #pragma unroll
        for (int u = 0; u < 4; ++u)
            av[u] = reinterpret_cast<const float4*>(att)[gf4base + u * 256u];
        #pragma unroll
        for (int u = 0; u < 4; ++u) {
            float q0 = 1.0f - fminf(fmaxf(av[u].x, EPSF), 1.0f - EPSF);
            float q1 = 1.0f - fminf(fmaxf(av[u].y, EPSF), 1.0f - EPSF);
            float q2 = 1.0f - fminf(fmaxf(av[u].z, EPSF), 1.0f - EPSF);
            float q3 = 1.0f - fminf(fmaxf(av[u].w, EPSF), 1.0f - EPSF);
            s -= __logf((q0 * q1) * (q2 * q3));
        }
    }

    float t = block_reduce(s, wsum);
    if (threadIdx.x == 0) partial[sbid] = t;
}

// ---- kernel C: finalize ------------------------------------------------------
__global__ __launch_bounds__(256)
void finalize_kernel(const float* __restrict__ bboxs,
                     const int* __restrict__ hp, const int* __restrict__ wp,
                     const float* __restrict__ partial,
                     const float* __restrict__ corr,
                     float* __restrict__ out)
{
    __shared__ int hasbox[B_SZ];
    __shared__ double red[256];
    if (threadIdx.x < B_SZ) hasbox[threadIdx.x] = 0;
    __syncthreads();
    float Wf = (float)(*wp), Hf = (float)(*hp);
    for (int i = (int)threadIdx.x; i < B_SZ * N_BOX; i += 256) {
        const float* bx = bboxs + i * 5;
        if (bx[4] != -1.0f && bx[0] <= Wf && bx[1] <= Hf && bx[2] <= Wf && bx[3] <= Hf)
            hasbox[i / N_BOX] = 1;        // benign race, same value
    }
    __syncthreads();

    double t = 0.0;
    for (int i = (int)threadIdx.x; i < N_STREAM; i += 256) {
        int l, start, bppShift;
        if (i < 2048)      { l = 0; start = 0;    bppShift = 7; }
        else if (i < 2560) { l = 1; start = 2048; bppShift = 5; }
        else if (i < 2688) { l = 2; start = 2560; bppShift = 3; }
        else if (i < 2720) { l = 3; start = 2688; bppShift = 1; }
        else               { l = 4; start = 2720; bppShift = 0; }
        int b = (i - start) >> bppShift;
        if (hasbox[b]) {
            int wl = 1024 >> l;
            t += (double)partial[i] / (double)(wl * wl);
        }
    }
    for (int i = (int)threadIdx.x; i < N_CORR2; i += 256) {
        int l, b;
        if (i < 128)      { l = 0; b = i >> 3; }
        else if (i < 160) { l = 1; b = (i - 128) >> 1; }
        else if (i < 176) { l = 2; b = i - 160; }
        else if (i < 192) { l = 3; b = i - 176; }
        else              { l = 4; b = i - 192; }
        if (hasbox[b]) {
            int wl = 1024 >> l;
            t += (double)corr[i] / (double)(wl * wl);
        }
    }
    red[threadIdx.x] = t;
    __syncthreads();
    for (int off = 128; off > 0; off >>= 1) {
        if ((int)threadIdx.x < off) red[threadIdx.x] += red[threadIdx.x + off];
        __syncthreads();
    }
    if (threadIdx.x == 0)
        out[0] = (float)(red[0] / (5.0 * (double)B_SZ));
}

// ---- launch ------------------------------------------------------------------
extern "C" void kernel_launch(void* const* d_in, const int* in_sizes, int n_in,
                              void* d_out, int out_size, void* d_ws, size_t ws_size,
                              hipStream_t stream)
{
    const float* a0 = (const float*)d_in[0];
    const float* a1 = (const float*)d_in[1];
    const float* a2 = (const float*)d_in[2];
    const float* a3 = (const float*)d_in[3];
    const float* a4 = (const float*)d_in[4];
    const float* bboxs = (const float*)d_in[5];
    const int* hp = (const int*)d_in[6];
    const int* wp = (const int*)d_in[7];

    float* partial = (float*)d_ws;            // N_STREAM floats, all written
    float* corr    = partial + N_STREAM;      // N_CORR2 floats, all written

    corr_kernel<<<N_CORR2, 256, 0, stream>>>(a0, a1, a2, a3, a4,
                                             bboxs, hp, wp, corr);
    stream_kernel<<<N_STREAM, 256, 0, stream>>>(a0, a1, a2, a3, a4, partial);
    finalize_kernel<<<1, 256, 0, stream>>>(bboxs, hp, wp, partial, corr,
                                           (float*)d_out);
}